// Round 4
// baseline (198.622 us; speedup 1.0000x reference)
//
#include <hip/hip_runtime.h>
#include <math.h>

// Shapes (fixed by the reference)
#define Bb   16
#define Ss   2048
#define Rr   196
#define Hh   768
#define Mtot (Bb * Rr)      // 3136 rows of img
#define NT   (Hh / 64)      // 12 n-tiles in K1
#define BK   128            // K1 k-blocking (6 iters over Hh=768)
#define LDA  136            // LDS row stride in bf16 (128 + 8 pad; 272 B = 17*16 keeps 16B align;
                            // frag reads & staging stores both hit the 8-accesses/bank b128 optimum)

typedef __attribute__((ext_vector_type(8))) short short8;
typedef __attribute__((ext_vector_type(4))) short short4v;
typedef __attribute__((ext_vector_type(4))) float f32x4;

__device__ inline short f2bf(float f) {
    unsigned u = __builtin_bit_cast(unsigned, f);
    u += 0x7fff + ((u >> 16) & 1);          // round-to-nearest-even
    return (short)(u >> 16);
}

// ---------------------------------------------------------------------------
// K0: fp32 -> bf16 conversion of img (602112 f32x4) and W_img (147456 f32x4)
// ---------------------------------------------------------------------------
__global__ __launch_bounds__(256) void k0_cvt(
    const f32x4* __restrict__ a, short4v* __restrict__ da, int na4,
    const f32x4* __restrict__ b, short4v* __restrict__ db)
{
    int gid = blockIdx.x * 256 + threadIdx.x;
    const f32x4* s;
    short4v* d;
    int i;
    if (gid < na4) { s = a; d = da; i = gid; }
    else           { s = b; d = db; i = gid - na4; }
    f32x4 x = s[i];
    short4v o;
    o.x = f2bf(x.x); o.y = f2bf(x.y); o.z = f2bf(x.z); o.w = f2bf(x.w);
    d[i] = o;
}

// ---------------------------------------------------------------------------
// K1: pre = img (M x K) * W^T (N x K), bf16 MFMA 16x16x32, fused epilogue
//     part[nt][m] = sum_{n in 64-tile} tanh(pre[m,n]) * w2[n]
// grid (49, 12), block 256 (4 waves), tile 64x64, BK=128, prefetched staging.
// ---------------------------------------------------------------------------
template <bool FROM_F32>
__global__ __launch_bounds__(256) void k1_mfma(
    const void* __restrict__ Ap, const void* __restrict__ Bp,
    const float* __restrict__ w_att, float* __restrict__ part)
{
    const int m0   = blockIdx.x * 64;
    const int n0   = blockIdx.y * 64;
    const int t    = threadIdx.x;
    const int lane = t & 63;
    const int wv   = t >> 6;
    const int wm   = (wv & 1) * 32;
    const int wn   = (wv >> 1) * 32;
    const int col  = lane & 15;
    const int quad = lane >> 4;

    __shared__ short As[64 * LDA];
    __shared__ short Bs[64 * LDA];
    __shared__ float red[64][2];

    f32x4 acc[2][2] = {};   // [mi][ni]

    const int sm = t >> 2;  // staging row 0..63
    const int sq = t & 3;   // staging k-quarter (32 bf16 each)

    short8 areg[4], breg[4];

    // prologue load (k0 = 0)
    if (FROM_F32) {
        const float* A = (const float*)Ap;
        const float* B = (const float*)Bp;
#pragma unroll
        for (int j = 0; j < 4; ++j) {
            float4 lo = *(const float4*)&A[(size_t)(m0 + sm) * Hh + sq * 32 + j * 8];
            float4 hi = *(const float4*)&A[(size_t)(m0 + sm) * Hh + sq * 32 + j * 8 + 4];
            areg[j][0] = f2bf(lo.x); areg[j][1] = f2bf(lo.y);
            areg[j][2] = f2bf(lo.z); areg[j][3] = f2bf(lo.w);
            areg[j][4] = f2bf(hi.x); areg[j][5] = f2bf(hi.y);
            areg[j][6] = f2bf(hi.z); areg[j][7] = f2bf(hi.w);
            lo = *(const float4*)&B[(size_t)(n0 + sm) * Hh + sq * 32 + j * 8];
            hi = *(const float4*)&B[(size_t)(n0 + sm) * Hh + sq * 32 + j * 8 + 4];
            breg[j][0] = f2bf(lo.x); breg[j][1] = f2bf(lo.y);
            breg[j][2] = f2bf(lo.z); breg[j][3] = f2bf(lo.w);
            breg[j][4] = f2bf(hi.x); breg[j][5] = f2bf(hi.y);
            breg[j][6] = f2bf(hi.z); breg[j][7] = f2bf(hi.w);
        }
    } else {
        const short* A = (const short*)Ap;
        const short* B = (const short*)Bp;
#pragma unroll
        for (int j = 0; j < 4; ++j) {
            areg[j] = *(const short8*)&A[(size_t)(m0 + sm) * Hh + sq * 32 + j * 8];
            breg[j] = *(const short8*)&B[(size_t)(n0 + sm) * Hh + sq * 32 + j * 8];
        }
    }

    for (int k0 = 0; k0 < Hh; k0 += BK) {
        __syncthreads();   // previous iteration's frag reads complete
#pragma unroll
        for (int j = 0; j < 4; ++j) {
            *(short8*)&As[sm * LDA + sq * 32 + j * 8] = areg[j];
            *(short8*)&Bs[sm * LDA + sq * 32 + j * 8] = breg[j];
        }
        __syncthreads();

        // prefetch next k-slab while MFMAs run
        if (k0 + BK < Hh) {
            const int kn = k0 + BK;
            if (FROM_F32) {
                const float* A = (const float*)Ap;
                const float* B = (const float*)Bp;
#pragma unroll
                for (int j = 0; j < 4; ++j) {
                    float4 lo = *(const float4*)&A[(size_t)(m0 + sm) * Hh + kn + sq * 32 + j * 8];
                    float4 hi = *(const float4*)&A[(size_t)(m0 + sm) * Hh + kn + sq * 32 + j * 8 + 4];
                    areg[j][0] = f2bf(lo.x); areg[j][1] = f2bf(lo.y);
                    areg[j][2] = f2bf(lo.z); areg[j][3] = f2bf(lo.w);
                    areg[j][4] = f2bf(hi.x); areg[j][5] = f2bf(hi.y);
                    areg[j][6] = f2bf(hi.z); areg[j][7] = f2bf(hi.w);
                    lo = *(const float4*)&B[(size_t)(n0 + sm) * Hh + kn + sq * 32 + j * 8];
                    hi = *(const float4*)&B[(size_t)(n0 + sm) * Hh + kn + sq * 32 + j * 8 + 4];
                    breg[j][0] = f2bf(lo.x); breg[j][1] = f2bf(lo.y);
                    breg[j][2] = f2bf(lo.z); breg[j][3] = f2bf(lo.w);
                    breg[j][4] = f2bf(hi.x); breg[j][5] = f2bf(hi.y);
                    breg[j][6] = f2bf(hi.z); breg[j][7] = f2bf(hi.w);
                }
            } else {
                const short* A = (const short*)Ap;
                const short* B = (const short*)Bp;
#pragma unroll
                for (int j = 0; j < 4; ++j) {
                    areg[j] = *(const short8*)&A[(size_t)(m0 + sm) * Hh + kn + sq * 32 + j * 8];
                    breg[j] = *(const short8*)&B[(size_t)(n0 + sm) * Hh + kn + sq * 32 + j * 8];
                }
            }
        }

#pragma unroll
        for (int kk = 0; kk < BK; kk += 32) {
            short8 a0 = *(const short8*)&As[(wm +      col) * LDA + kk + quad * 8];
            short8 a1 = *(const short8*)&As[(wm + 16 + col) * LDA + kk + quad * 8];
            short8 b0 = *(const short8*)&Bs[(wn +      col) * LDA + kk + quad * 8];
            short8 b1 = *(const short8*)&Bs[(wn + 16 + col) * LDA + kk + quad * 8];
            acc[0][0] = __builtin_amdgcn_mfma_f32_16x16x32_bf16(a0, b0, acc[0][0], 0, 0, 0);
            acc[0][1] = __builtin_amdgcn_mfma_f32_16x16x32_bf16(a0, b1, acc[0][1], 0, 0, 0);
            acc[1][0] = __builtin_amdgcn_mfma_f32_16x16x32_bf16(a1, b0, acc[1][0], 0, 0, 0);
            acc[1][1] = __builtin_amdgcn_mfma_f32_16x16x32_bf16(a1, b1, acc[1][1], 0, 0, 0);
        }
    }

    // Epilogue: tanh * w2, reduce over this block's 64 n-columns.
    const float* w2 = w_att + Hh;
    float w2v0 = w2[n0 + wn + col];
    float w2v1 = w2[n0 + wn + 16 + col];

#pragma unroll
    for (int mi = 0; mi < 2; ++mi) {
#pragma unroll
        for (int r = 0; r < 4; ++r) {
            float s = tanhf(acc[mi][0][r]) * w2v0 + tanhf(acc[mi][1][r]) * w2v1;
            s += __shfl_xor(s, 1, 64);
            s += __shfl_xor(s, 2, 64);
            s += __shfl_xor(s, 4, 64);
            s += __shfl_xor(s, 8, 64);
            if (col == 0)
                red[wm + mi * 16 + quad * 4 + r][wn >> 5] = s;
        }
    }
    __syncthreads();
    if (t < 64)
        part[blockIdx.y * Mtot + m0 + t] = red[t][0] + red[t][1];
}

// ---------------------------------------------------------------------------
// K2: per batch b: scores[r] = sum_nt part[nt][b*Rr+r]; p = softmax(scores);
//     v[b,h] = sum_r p[r] * img[b,r,h].   grid (16, 12).
// ---------------------------------------------------------------------------
__global__ __launch_bounds__(256) void k2_softmax_v(
    const float* __restrict__ part,
    const float* __restrict__ img,
    float* __restrict__ v)
{
    const int b = blockIdx.x;
    const int t = threadIdx.x;

    __shared__ float p[Rr];
    __shared__ float redbuf[256];
    __shared__ float a2[4][65];

    float myv = -INFINITY;
    if (t < Rr) {
        float s = 0.f;
#pragma unroll
        for (int nt = 0; nt < NT; ++nt) s += part[nt * Mtot + b * Rr + t];
        p[t] = s;
        myv = s;
    }
    redbuf[t] = myv;
    __syncthreads();
    for (int off = 128; off > 0; off >>= 1) {
        if (t < off) redbuf[t] = fmaxf(redbuf[t], redbuf[t + off]);
        __syncthreads();
    }
    const float mx = redbuf[0];
    __syncthreads();

    float e = 0.f;
    if (t < Rr) e = expf(p[t] - mx);
    redbuf[t] = e;
    __syncthreads();
    for (int off = 128; off > 0; off >>= 1) {
        if (t < off) redbuf[t] += redbuf[t + off];
        __syncthreads();
    }
    const float inv = 1.f / redbuf[0];
    __syncthreads();
    if (t < Rr) p[t] = e * inv;
    __syncthreads();

    // weighted sum over r, split in 4 groups of 49
    const int h  = blockIdx.y * 64 + (t & 63);
    const int rg = t >> 6;
    const float* imgb = img + (size_t)b * Rr * Hh + h;
    float s = 0.f;
#pragma unroll 7
    for (int r = rg * 49; r < rg * 49 + 49; ++r)
        s = fmaf(p[r], imgb[(size_t)r * Hh], s);
    a2[rg][t & 63] = s;
    __syncthreads();
    if (t < 64)
        v[b * Hh + blockIdx.y * 64 + t] = a2[0][t] + a2[1][t] + a2[2][t] + a2[3][t];
}

// ---------------------------------------------------------------------------
// K3: out[b,s,:] = v[b,:]  — 100 MB of nontemporal vector stores.
// ---------------------------------------------------------------------------
__global__ __launch_bounds__(256) void k3_bcast(
    const f32x4* __restrict__ v4,
    f32x4* __restrict__ out)
{
    const int gid   = blockIdx.x * 256 + threadIdx.x;   // < 6291456
    const int per_b = Ss * (Hh / 4);                    // 393216 f32x4 per batch
    const int b     = gid / per_b;
    const int h4    = gid % (Hh / 4);                   // 0..191
    f32x4 val = v4[b * (Hh / 4) + h4];
    __builtin_nontemporal_store(val, &out[gid]);
}

// ---------------------------------------------------------------------------
extern "C" void kernel_launch(void* const* d_in, const int* in_sizes, int n_in,
                              void* d_out, int out_size, void* d_ws, size_t ws_size,
                              hipStream_t stream)
{
    // Input order: text_features, img_features, W_text, b_text, W_img, w_att, b_att
    const float* img   = (const float*)d_in[1];
    const float* W_img = (const float*)d_in[4];
    const float* w_att = (const float*)d_in[5];
    // text_features / W_text / b_text / b_att are mathematically dead:
    // softmax over r is invariant to the per-(b,s) text score and to b_att.

    float* part = (float*)d_ws;                  // NT*Mtot floats   = 150528 B
    float* v    = part + NT * Mtot;              // Bb*Hh floats     =  49152 B
    size_t off  = ((size_t)(NT * Mtot + Bb * Hh) * 4 + 15) & ~(size_t)15;
    short* imgbf = (short*)((char*)d_ws + off);                  // 4816896 B
    short* Wbf   = imgbf + (size_t)Mtot * Hh;                    // 1179648 B
    const size_t need = off + ((size_t)Mtot * Hh + (size_t)Hh * Hh) * 2;

    float* out = (float*)d_out;
    const bool usebf = (ws_size >= need);        // constant across calls -> graph-safe

    if (usebf) {
        const int na4 = (Mtot * Hh) / 4;         // 602112
        const int nb4 = (Hh * Hh) / 4;           // 147456
        k0_cvt<<<(na4 + nb4) / 256, 256, 0, stream>>>(
            (const f32x4*)img, (short4v*)imgbf, na4,
            (const f32x4*)W_img, (short4v*)Wbf);
        k1_mfma<false><<<dim3(Mtot / 64, NT), 256, 0, stream>>>(imgbf, Wbf, w_att, part);
    } else {
        k1_mfma<true><<<dim3(Mtot / 64, NT), 256, 0, stream>>>(img, W_img, w_att, part);
    }

    k2_softmax_v<<<dim3(Bb, NT), 256, 0, stream>>>(part, img, v);

    const int total4 = Bb * Ss * (Hh / 4);       // 6291456
    k3_bcast<<<total4 / 256, 256, 0, stream>>>((const f32x4*)v, (f32x4*)out);
}

// Round 5
// 195.886 us; speedup vs baseline: 1.0140x; 1.0140x over previous
//
#include <hip/hip_runtime.h>
#include <math.h>

// Shapes (fixed by the reference)
#define Bb   16
#define Ss   2048
#define Rr   196
#define Hh   768
#define Mtot (Bb * Rr)      // 3136 rows of img
#define NT   (Hh / 64)      // 12 n-tiles in K1
#define LDA  72             // LDS row stride in bf16 (64 + 8 pad; keeps 16B align)
#define SZ   8              // s-split for the fused broadcast (Ss/SZ = 256 rows/block)

typedef __attribute__((ext_vector_type(8))) short short8;
typedef __attribute__((ext_vector_type(4))) short short4v;
typedef __attribute__((ext_vector_type(4))) float f32x4;

__device__ inline short f2bf(float f) {
    unsigned u = __builtin_bit_cast(unsigned, f);
    u += 0x7fff + ((u >> 16) & 1);          // round-to-nearest-even
    return (short)(u >> 16);
}

// ---------------------------------------------------------------------------
// K0: fp32 -> bf16 conversion of img (602112 f32x4) and W_img (147456 f32x4)
// ---------------------------------------------------------------------------
__global__ __launch_bounds__(256) void k0_cvt(
    const f32x4* __restrict__ a, short4v* __restrict__ da, int na4,
    const f32x4* __restrict__ b, short4v* __restrict__ db)
{
    int gid = blockIdx.x * 256 + threadIdx.x;
    const f32x4* s;
    short4v* d;
    int i;
    if (gid < na4) { s = a; d = da; i = gid; }
    else           { s = b; d = db; i = gid - na4; }
    f32x4 x = s[i];
    short4v o;
    o.x = f2bf(x.x); o.y = f2bf(x.y); o.z = f2bf(x.z); o.w = f2bf(x.w);
    d[i] = o;
}

// ---------------------------------------------------------------------------
// K1 (R3-measured-best): pre = img (M x K) * W^T (N x K), bf16 MFMA 16x16x32,
// fused epilogue part[nt][m] = sum_{n in 64-tile} tanh(pre[m,n]) * w2[n]
// grid (49, 12), block 256 (4 waves), tile 64x64, BK=64.
// ---------------------------------------------------------------------------
template <bool FROM_F32>
__global__ __launch_bounds__(256) void k1_mfma(
    const void* __restrict__ Ap, const void* __restrict__ Bp,
    const float* __restrict__ w_att, float* __restrict__ part)
{
    const int m0   = blockIdx.x * 64;
    const int n0   = blockIdx.y * 64;
    const int t    = threadIdx.x;
    const int lane = t & 63;
    const int wv   = t >> 6;
    const int wm   = (wv & 1) * 32;
    const int wn   = (wv >> 1) * 32;
    const int col  = lane & 15;
    const int quad = lane >> 4;

    __shared__ short As[64 * LDA];
    __shared__ short Bs[64 * LDA];
    __shared__ float red[64][2];

    f32x4 acc[2][2] = {};   // [mi][ni]

    const int sm = t >> 2;  // staging row 0..63
    const int sq = t & 3;   // staging k-quarter 0..3

    for (int k0 = 0; k0 < Hh; k0 += 64) {
        short8 areg[2], breg[2];
        if (FROM_F32) {
            const float* A = (const float*)Ap;
            const float* B = (const float*)Bp;
#pragma unroll
            for (int j = 0; j < 2; ++j) {
                float4 lo = *(const float4*)&A[(size_t)(m0 + sm) * Hh + k0 + sq * 16 + j * 8];
                float4 hi = *(const float4*)&A[(size_t)(m0 + sm) * Hh + k0 + sq * 16 + j * 8 + 4];
                areg[j][0] = f2bf(lo.x); areg[j][1] = f2bf(lo.y);
                areg[j][2] = f2bf(lo.z); areg[j][3] = f2bf(lo.w);
                areg[j][4] = f2bf(hi.x); areg[j][5] = f2bf(hi.y);
                areg[j][6] = f2bf(hi.z); areg[j][7] = f2bf(hi.w);
                lo = *(const float4*)&B[(size_t)(n0 + sm) * Hh + k0 + sq * 16 + j * 8];
                hi = *(const float4*)&B[(size_t)(n0 + sm) * Hh + k0 + sq * 16 + j * 8 + 4];
                breg[j][0] = f2bf(lo.x); breg[j][1] = f2bf(lo.y);
                breg[j][2] = f2bf(lo.z); breg[j][3] = f2bf(lo.w);
                breg[j][4] = f2bf(hi.x); breg[j][5] = f2bf(hi.y);
                breg[j][6] = f2bf(hi.z); breg[j][7] = f2bf(hi.w);
            }
        } else {
            const short* A = (const short*)Ap;
            const short* B = (const short*)Bp;
#pragma unroll
            for (int j = 0; j < 2; ++j) {
                areg[j] = *(const short8*)&A[(size_t)(m0 + sm) * Hh + k0 + sq * 16 + j * 8];
                breg[j] = *(const short8*)&B[(size_t)(n0 + sm) * Hh + k0 + sq * 16 + j * 8];
            }
        }
        __syncthreads();   // previous iteration's frag reads complete
#pragma unroll
        for (int j = 0; j < 2; ++j) {
            *(short8*)&As[sm * LDA + sq * 16 + j * 8] = areg[j];
            *(short8*)&Bs[sm * LDA + sq * 16 + j * 8] = breg[j];
        }
        __syncthreads();
#pragma unroll
        for (int kk = 0; kk < 64; kk += 32) {
            short8 a0 = *(const short8*)&As[(wm +      col) * LDA + kk + quad * 8];
            short8 a1 = *(const short8*)&As[(wm + 16 + col) * LDA + kk + quad * 8];
            short8 b0 = *(const short8*)&Bs[(wn +      col) * LDA + kk + quad * 8];
            short8 b1 = *(const short8*)&Bs[(wn + 16 + col) * LDA + kk + quad * 8];
            acc[0][0] = __builtin_amdgcn_mfma_f32_16x16x32_bf16(a0, b0, acc[0][0], 0, 0, 0);
            acc[0][1] = __builtin_amdgcn_mfma_f32_16x16x32_bf16(a0, b1, acc[0][1], 0, 0, 0);
            acc[1][0] = __builtin_amdgcn_mfma_f32_16x16x32_bf16(a1, b0, acc[1][0], 0, 0, 0);
            acc[1][1] = __builtin_amdgcn_mfma_f32_16x16x32_bf16(a1, b1, acc[1][1], 0, 0, 0);
        }
    }

    // Epilogue: tanh * w2, reduce over this block's 64 n-columns.
    const float* w2 = w_att + Hh;
    float w2v0 = w2[n0 + wn + col];
    float w2v1 = w2[n0 + wn + 16 + col];

#pragma unroll
    for (int mi = 0; mi < 2; ++mi) {
#pragma unroll
        for (int r = 0; r < 4; ++r) {
            float s = tanhf(acc[mi][0][r]) * w2v0 + tanhf(acc[mi][1][r]) * w2v1;
            s += __shfl_xor(s, 1, 64);
            s += __shfl_xor(s, 2, 64);
            s += __shfl_xor(s, 4, 64);
            s += __shfl_xor(s, 8, 64);
            if (col == 0)
                red[wm + mi * 16 + quad * 4 + r][wn >> 5] = s;
        }
    }
    __syncthreads();
    if (t < 64)
        part[blockIdx.y * Mtot + m0 + t] = red[t][0] + red[t][1];
}

// ---------------------------------------------------------------------------
// K23: fused softmax + v-tile + broadcast-store.
// grid (16, 12, SZ): block (b, hy, z) computes p = softmax_r(scores[b,:]),
// v-tile = sum_r p[r]*img[b,r,hy*64:+64], then writes that tile into
// out[b, z*256:(z+1)*256, hy*64:+64].  Phase-1 redundancy across z is tiny
// (L2-resident re-reads, ~40 MFLOP total).
// ---------------------------------------------------------------------------
__global__ __launch_bounds__(256) void k23_softmax_bcast(
    const float* __restrict__ part,
    const float* __restrict__ img,
    float* __restrict__ out)
{
    const int b  = blockIdx.x;
    const int hb = blockIdx.y * 64;
    const int t  = threadIdx.x;

    __shared__ float p[Rr];
    __shared__ float redbuf[256];
    __shared__ float a2[4][65];
    __shared__ float vtile[64];

    float myv = -INFINITY;
    if (t < Rr) {
        float s = 0.f;
#pragma unroll
        for (int nt = 0; nt < NT; ++nt) s += part[nt * Mtot + b * Rr + t];
        p[t] = s;
        myv = s;
    }
    redbuf[t] = myv;
    __syncthreads();
    for (int off = 128; off > 0; off >>= 1) {
        if (t < off) redbuf[t] = fmaxf(redbuf[t], redbuf[t + off]);
        __syncthreads();
    }
    const float mx = redbuf[0];
    __syncthreads();

    float e = 0.f;
    if (t < Rr) e = expf(p[t] - mx);
    redbuf[t] = e;
    __syncthreads();
    for (int off = 128; off > 0; off >>= 1) {
        if (t < off) redbuf[t] += redbuf[t + off];
        __syncthreads();
    }
    const float inv = 1.f / redbuf[0];
    __syncthreads();
    if (t < Rr) p[t] = e * inv;
    __syncthreads();

    // v-tile: weighted sum over r, split in 4 groups of 49
    const int h  = hb + (t & 63);
    const int rg = t >> 6;
    const float* imgb = img + (size_t)b * Rr * Hh + h;
    float s = 0.f;
#pragma unroll 7
    for (int r = rg * 49; r < rg * 49 + 49; ++r)
        s = fmaf(p[r], imgb[(size_t)r * Hh], s);
    a2[rg][t & 63] = s;
    __syncthreads();
    if (t < 64)
        vtile[t] = a2[0][t] + a2[1][t] + a2[2][t] + a2[3][t];
    __syncthreads();

    // broadcast: out[b, s0:s0+256, hb:hb+64]
    const int hsub = t & 15;            // which f32x4 of the 64-float tile
    const int srow = t >> 4;            // 0..15
    f32x4 val = *(const f32x4*)&vtile[hsub * 4];
    f32x4* ob = (f32x4*)out + (size_t)b * Ss * (Hh / 4) + (hb >> 2) + hsub;
    const int s0 = blockIdx.z * (Ss / SZ);      // z*256
#pragma unroll
    for (int s2 = s0 + srow; s2 < s0 + Ss / SZ; s2 += 16)
        __builtin_nontemporal_store(val, &ob[(size_t)s2 * (Hh / 4)]);
}

// ---------------------------------------------------------------------------
extern "C" void kernel_launch(void* const* d_in, const int* in_sizes, int n_in,
                              void* d_out, int out_size, void* d_ws, size_t ws_size,
                              hipStream_t stream)
{
    // Input order: text_features, img_features, W_text, b_text, W_img, w_att, b_att
    const float* img   = (const float*)d_in[1];
    const float* W_img = (const float*)d_in[4];
    const float* w_att = (const float*)d_in[5];
    // text_features / W_text / b_text / b_att are mathematically dead:
    // softmax over r is invariant to the per-(b,s) text score and to b_att.

    float* part = (float*)d_ws;                  // NT*Mtot floats = 150528 B
    size_t off  = ((size_t)(NT * Mtot) * 4 + 15) & ~(size_t)15;
    short* imgbf = (short*)((char*)d_ws + off);                  // 4816896 B
    short* Wbf   = imgbf + (size_t)Mtot * Hh;                    // 1179648 B
    const size_t need = off + ((size_t)Mtot * Hh + (size_t)Hh * Hh) * 2;

    float* out = (float*)d_out;
    const bool usebf = (ws_size >= need);        // constant across calls -> graph-safe

    if (usebf) {
        const int na4 = (Mtot * Hh) / 4;         // 602112
        const int nb4 = (Hh * Hh) / 4;           // 147456
        k0_cvt<<<(na4 + nb4) / 256, 256, 0, stream>>>(
            (const f32x4*)img, (short4v*)imgbf, na4,
            (const f32x4*)W_img, (short4v*)Wbf);
        k1_mfma<false><<<dim3(Mtot / 64, NT), 256, 0, stream>>>(imgbf, Wbf, w_att, part);
    } else {
        k1_mfma<true><<<dim3(Mtot / 64, NT), 256, 0, stream>>>(img, W_img, w_att, part);
    }

    k23_softmax_bcast<<<dim3(Bb, NT, SZ), 256, 0, stream>>>(part, img, out);
}